// Round 1
// 752.774 us; speedup vs baseline: 1.1622x; 1.1622x over previous
//
#include <hip/hip_runtime.h>
#include <hip/hip_bf16.h>

// GraphConvLayer B=4,N=128,D=512,H=8. Input dtype (bf16|fp32) runtime-detected
// -> flag in ws; output dtype follows input dtype.
// f==1: E pre-converted to bf16 into d_out's outE region, chunk-layout:
//   chunk c (64 rows) occupies bytes [1048576 + c*131072, +131072):
//   [Ebf16 64x1024B | u 64x1024B]. outE fp32 rows of chunk c = same byte range;
//   k6 block owns one chunk: reads Ebf16+u, barrier, overwrites with fp32 out.
// f==0: E read from d_in (bf16); u chunks at dout+524288+c*65536.
// XCD-locality chain: cvt_edge, k3, k6 grids swizzled so chunk c is written and
// read on XCD (c>>1)&7 (k3 block bm -> XCD bm&7; its chunks are 2bm,2bm+1).
// k3 (this round): BK=32, 16 K-iters, 3-deep counted-vmcnt pipeline (T3+T4):
//   stage(t+2) issued after raw s_barrier, s_waitcnt vmcnt(4) at iter top (never
//   0 until last tile). LDS 52KB (3x8K A | 3x8K B | 4K We2-tile) -> 3 blocks/CU.
//   Attn epilogue: shfl-reduce replaced by bf16 e-image in LDS + 8x MFMA vs
//   zero-padded We2 tile (same pattern as u-path image).
// u-epilogue goes through LDS -> 16B/lane coalesced global stores.
// Attn logits: per-block partial written to 4-slot logits4 (no atomics).

typedef __bf16  bf16x8 __attribute__((ext_vector_type(8)));
typedef float   f32x4  __attribute__((ext_vector_type(4)));
typedef __hip_bfloat16 bfloat;

#define AS1 __attribute__((address_space(1)))
#define AS3 __attribute__((address_space(3)))

__device__ __forceinline__ void g2l16(const void* g, void* l) {
  __builtin_amdgcn_global_load_lds((AS1 void*)g, (AS3 void*)l, 16, 0, 0);
}

__device__ __forceinline__ float ldf(const void* p, size_t i, int f) {
  return f ? ((const float*)p)[i] : __bfloat162float(((const bfloat*)p)[i]);
}
__device__ __forceinline__ void stf(void* p, size_t i, float v, int f) {
  if (f) ((float*)p)[i] = v;
  else   ((bfloat*)p)[i] = __float2bfloat16(v);
}

// tanh-form GELU (max abs err ~3e-4 vs exact erf form; well under threshold)
__device__ __forceinline__ float gelu_f(float x) {
  float y = 0.7978845608028654f * (x + 0.044715f * x * x * x);
  float e = __expf(2.0f * y);
  float t = 1.0f - 2.0f / (e + 1.0f);
  return 0.5f * x * (1.0f + t);
}

__global__ __launch_bounds__(256) void detect_dtype(const unsigned short* nu, int* flag) {
  __shared__ int bad;
  if (threadIdx.x == 0) bad = 0;
  __syncthreads();
  int local = 0;
  for (int i = threadIdx.x; i < 4096; i += 256) {
    int ex = (nu[i] >> 7) & 0xFF;
    if (ex >= 0xC0) local = 1;
  }
  if (local) atomicOr(&bad, 1);
  __syncthreads();
  if (threadIdx.x == 0) *flag = bad;
}

// f==1 only: E fp32 -> bf16 chunk layout in dout. Grid 16384, XCD-aligned:
// chunk c handled by blocks with blockIdx%8 == (c>>1)&7.
__global__ __launch_bounds__(256) void cvt_edge(const float* E, const int* flag, void* dout) {
  if (*flag == 0) return;
  const int e = blockIdx.x & 7;
  const int x = blockIdx.x >> 3;          // 0..2047
  const int m = x >> 5;                   // 0..63
  const int h = (x >> 4) & 1;
  const int s = x & 15;                   // 16 blocks per chunk
  const int c = 2 * e + 16 * m + h;       // chunk 0..1023
  const int t = threadIdx.x;
  const int rloc = s * 4 + (t >> 6);      // row within chunk 0..63
  const int c8 = t & 63;
  const float* src = E + ((size_t)c * 64 + rloc) * 512 + (size_t)c8 * 8;
  f32x4 lo = *(const f32x4*)src;
  f32x4 hi = *(const f32x4*)(src + 4);
  bf16x8 v;
  v[0] = (__bf16)lo[0]; v[1] = (__bf16)lo[1]; v[2] = (__bf16)lo[2]; v[3] = (__bf16)lo[3];
  v[4] = (__bf16)hi[0]; v[5] = (__bf16)hi[1]; v[6] = (__bf16)hi[2]; v[7] = (__bf16)hi[3];
  char* eb = (char*)dout + 1048576;
  *(bf16x8*)(eb + (size_t)c * 131072 + (size_t)rloc * 1024 + (size_t)c8 * 16) = v;
}

__global__ __launch_bounds__(256) void transpose3(const void* We1, const void* Wu1,
                                                  const void* Wu2, const int* flag,
                                                  bfloat* WtA, bfloat* WtB, bfloat* WtC) {
  const int f = *flag;
  int idx = blockIdx.x * 256 + threadIdx.x;
  int m = idx >> 18;
  int r = idx & 262143;
  int n = r >> 9, k = r & 511;
  size_t si = (size_t)k * 512 + n;
  float v;
  bfloat* dst;
  if (m == 0)      { v = ldf(We1, 524288 + si, f); dst = WtA; }
  else if (m == 1) { v = ldf(Wu1, 524288 + si, f); dst = WtB; }
  else             { v = ldf(Wu2, si, f);          dst = WtC; }
  dst[(size_t)n * 512 + k] = __float2bfloat16(v);
}

__global__ __launch_bounds__(256) void small_gemm(const void* A, int amode, const void* W,
                                                  size_t woff, const void* bias,
                                                  const int* flag, float* out) {
  const int f = *flag;
  const int af = amode ? 1 : f;
  __shared__ float sA[4][512];
  const int t = threadIdx.x;
  const int r0 = blockIdx.x * 4;
  for (int idx = t; idx < 2048; idx += 256)
    sA[idx >> 9][idx & 511] = ldf(A, (size_t)(r0 + (idx >> 9)) * 512 + (idx & 511), af);
  __syncthreads();
  float acc0[4] = {0.f, 0.f, 0.f, 0.f}, acc1[4] = {0.f, 0.f, 0.f, 0.f};
#pragma unroll 4
  for (int k = 0; k < 512; ++k) {
    float w0 = ldf(W, woff + (size_t)k * 512 + t, f);
    float w1 = ldf(W, woff + (size_t)k * 512 + t + 256, f);
#pragma unroll
    for (int r = 0; r < 4; ++r) {
      acc0[r] += sA[r][k] * w0;
      acc1[r] += sA[r][k] * w1;
    }
  }
  float b0 = bias ? ldf(bias, t, f) : 0.f;
  float b1 = bias ? ldf(bias, t + 256, f) : 0.f;
#pragma unroll
  for (int r = 0; r < 4; ++r) {
    out[(size_t)(r0 + r) * 512 + t] = acc0[r] + b0;
    out[(size_t)(r0 + r) * 512 + t + 256] = acc1[r] + b1;
  }
}

// 5 h-dependent 512^3 GEMMs in one launch
__global__ __launch_bounds__(256) void fused5(const float* h, const void* We1, const void* We1b,
                                              const void* Wu1, const void* Wu1b, const void* Wm,
                                              const void* Wmb, const int* flag, float* P1,
                                              float* Q1, float* P2, float* Q2, float* msgv) {
  const int f = *flag;
  const void* W;
  size_t woff = 0;
  const void* bias = nullptr;
  float* out;
  switch (blockIdx.y) {
    case 0:  W = We1; bias = We1b; out = P1; break;
    case 1:  W = We1; woff = 262144; out = Q1; break;
    case 2:  W = Wu1; bias = Wu1b; out = P2; break;
    case 3:  W = Wu1; woff = 262144; out = Q2; break;
    default: W = Wm;  bias = Wmb;  out = msgv; break;
  }
  __shared__ float sA[4][512];
  const int t = threadIdx.x;
  const int r0 = blockIdx.x * 4;
  for (int idx = t; idx < 2048; idx += 256)
    sA[idx >> 9][idx & 511] = h[(size_t)(r0 + (idx >> 9)) * 512 + (idx & 511)];
  __syncthreads();
  float acc0[4] = {0.f, 0.f, 0.f, 0.f}, acc1[4] = {0.f, 0.f, 0.f, 0.f};
#pragma unroll 4
  for (int k = 0; k < 512; ++k) {
    float w0 = ldf(W, woff + (size_t)k * 512 + t, f);
    float w1 = ldf(W, woff + (size_t)k * 512 + t + 256, f);
#pragma unroll
    for (int r = 0; r < 4; ++r) {
      acc0[r] += sA[r][k] * w0;
      acc1[r] += sA[r][k] * w1;
    }
  }
  float b0 = bias ? ldf(bias, t, f) : 0.f;
  float b1 = bias ? ldf(bias, t + 256, f) : 0.f;
#pragma unroll
  for (int r = 0; r < 4; ++r) {
    out[(size_t)(r0 + r) * 512 + t] = acc0[r] + b0;
    out[(size_t)(r0 + r) * 512 + t + 256] = acc1[r] + b1;
  }
}

// K3: 128x128 tile, BK=32, 16 K-iters, 3-deep counted-vmcnt LDS pipeline.
// LDS 52KB: A bufs [0,8K,16K), B bufs [24K,32K,40K), We2 tile [48K,52K).
// Epilogues reuse [0,32K) as the 128x128 bf16 swizzled image.
__global__ __launch_bounds__(256) void k3_edge_mlp(const void* E, const bfloat* WtA,
                                                   const bfloat* WtB, const float* P1,
                                                   const float* Q1, const float* P2,
                                                   const float* Q2, const void* We2,
                                                   const int* flag, float* logits4, void* dout) {
  const int f = *flag;
  __shared__ __align__(16) char smem[53248];
  f32x4 acc[4][4];
#pragma unroll
  for (int mi = 0; mi < 4; ++mi)
#pragma unroll
    for (int ni = 0; ni < 4; ++ni) acc[mi][ni] = (f32x4){0.f, 0.f, 0.f, 0.f};

  const int idx0 = blockIdx.x;                 // 0..4095
  const int bm = (idx0 >> 6) * 8 + (idx0 & 7); // XCD = bm&7
  const int bn = (idx0 >> 3) & 7;              // <4 attn, >=4 u
  const bool attn = bn < 4;
  const bfloat* Bg = attn ? WtA + (size_t)bn * 65536 : WtB + (size_t)(bn - 4) * 65536;
  const bfloat* Eb = (const bfloat*)E;
  const char* eb = (const char*)dout + 1048576;

  const int t = threadIdx.x;
  const int lane = t & 63;
  const int wave = t >> 6;
  const int wrow = wave >> 1, wcol = wave & 1;
  const int l15 = lane & 15;
  const int q = lane >> 4;
  const int blockcol = (attn ? bn : (bn - 4)) * 128;

  // per-thread stage sources (byte pointers); +64B per kt (32 bf16).
  // chunk L = c*256+t -> row = L>>2, phys slot p = L&3 holds data chunk g = p^(row&3).
  const int row0 = t >> 2, p0 = t & 3, g0 = p0 ^ (row0 & 3);
  const int row1 = 64 + row0, g1 = p0 ^ (row1 & 3);
  const char* srcB0 = (const char*)Bg + ((size_t)row0 * 512 + g0 * 8) * 2;
  const char* srcB1 = (const char*)Bg + ((size_t)row1 * 512 + g1 * 8) * 2;
  const char* srcA0;
  const char* srcA1;
  const int gr0 = bm * 128 + row0, gr1 = gr0 + 64;
  if (f) {
    srcA0 = eb + (size_t)(gr0 >> 6) * 131072 + (size_t)(gr0 & 63) * 1024 + (size_t)g0 * 16;
    srcA1 = eb + (size_t)(gr1 >> 6) * 131072 + (size_t)(gr1 & 63) * 1024 + (size_t)g1 * 16;
  } else {
    srcA0 = (const char*)Eb + ((size_t)gr0 * 512 + g0 * 8) * 2;
    srcA1 = (const char*)Eb + ((size_t)gr1 * 512 + g1 * 8) * 2;
  }
  const int dst0 = wave * 1024;           // + lane*16 added by HW
  const int dst1 = 4096 + wave * 1024;

  auto stage = [&](int kt2, int sel2) {
    char* dA = smem + sel2 * 8192;
    char* dB = smem + 24576 + sel2 * 8192;
    const int koff = kt2 * 64;
    g2l16(srcA0 + koff, dA + dst0);
    g2l16(srcA1 + koff, dA + dst1);
    g2l16(srcB0 + koff, dB + dst0);
    g2l16(srcB1 + koff, dB + dst1);
  };

  stage(0, 0);
  stage(1, 1);

  if (attn) {
    // fill sWe2 [16][128] bf16 at 48K: row n (h, zero-pad n>=8), swizzled like image
    for (int idx = t; idx < 2048; idx += 256) {
      const int n = idx >> 7, k = idx & 127;
      float v = (n < 8) ? ldf(We2, (size_t)(blockcol + k) * 8 + n, f) : 0.f;
      *(bfloat*)(smem + 49152 + (size_t)n * 256 + (((k >> 3) ^ n) * 16) + (k & 7) * 2) =
          __float2bfloat16(v);
    }
  }

  // frag byte offsets within an 8KB buffer (row stride 64B, XOR'd chunk)
  const int fA = (wrow * 64 + l15) * 64 + ((q ^ (l15 & 3)) * 16);
  const int fB = (wcol * 64 + l15) * 64 + ((q ^ (l15 & 3)) * 16);

#pragma unroll
  for (int kt = 0; kt < 16; ++kt) {
    if (kt < 15) asm volatile("s_waitcnt vmcnt(4)" ::: "memory");
    else         asm volatile("s_waitcnt vmcnt(0)" ::: "memory");
    __builtin_amdgcn_s_barrier();
    if (kt < 14) stage(kt + 2, (kt + 2) % 3);
    const char* A = smem + (kt % 3) * 8192;
    const char* B = smem + 24576 + (kt % 3) * 8192;
    bf16x8 afr[4], bfr[4];
#pragma unroll
    for (int mi = 0; mi < 4; ++mi) afr[mi] = *(const bf16x8*)(A + fA + mi * 1024);
#pragma unroll
    for (int ni = 0; ni < 4; ++ni) bfr[ni] = *(const bf16x8*)(B + fB + ni * 1024);
#pragma unroll
    for (int mi = 0; mi < 4; ++mi)
#pragma unroll
      for (int ni = 0; ni < 4; ++ni)
        acc[mi][ni] =
            __builtin_amdgcn_mfma_f32_16x16x32_bf16(afr[mi], bfr[ni], acc[mi][ni], 0, 0, 0);
  }

  const int b = bm >> 7;
  const float* P = attn ? P1 : P2;
  const float* Qm = attn ? Q1 : Q2;
  // hoisted P (row-constant per block): global col = blockcol + wcol*64 + ni*16 + l15
  float pv[4];
#pragma unroll
  for (int ni = 0; ni < 4; ++ni)
    pv[ni] = P[(size_t)bm * 512 + blockcol + wcol * 64 + ni * 16 + l15];

  __syncthreads();  // last tile's frag reads retired before smem reuse as image

  if (!attn) {
    // write phase: val(j, cc) at j*256 + ((cc>>3)^(j&15))*16 + (cc&7)*2
#pragma unroll
    for (int mi = 0; mi < 4; ++mi)
#pragma unroll
      for (int rr = 0; rr < 4; ++rr) {
        const int j = wrow * 64 + mi * 16 + q * 4 + rr;
#pragma unroll
        for (int ni = 0; ni < 4; ++ni) {
          const int cc = wcol * 64 + ni * 16 + l15;
          const int c = blockcol + cc;
          float x = acc[mi][ni][rr] + pv[ni] + Qm[((size_t)b * 128 + j) * 512 + c];
          *(bfloat*)(smem + (size_t)j * 256 + (((cc >> 3) ^ (j & 15)) * 16) + (cc & 7) * 2) =
              __float2bfloat16(gelu_f(x));
        }
      }
    __syncthreads();
    // read phase: 16B/lane, lanes 0..15 cover one full 256B local row -> coalesced
    char* ubase = (char*)dout + (f ? (1048576 + 65536) : 524288);
    const size_t blkstride = f ? 131072 : 65536;
#pragma unroll
    for (int rd = 0; rd < 8; ++rd) {
      const int j = rd * 16 + (t >> 4);
      const int ch = t & 15;
      f32x4 v = *(const f32x4*)(smem + (size_t)j * 256 + ((ch ^ (j & 15)) * 16));
      const size_t m = (size_t)bm * 128 + j;
      *(f32x4*)(ubase + (m >> 6) * blkstride + (m & 63) * 1024 + (size_t)blockcol * 2 +
                (size_t)ch * 16) = v;
    }
  } else {
    // write lrelu(e) bf16 into the image, then logits-partial = image @ sWe2 via MFMA
#pragma unroll
    for (int mi = 0; mi < 4; ++mi)
#pragma unroll
      for (int rr = 0; rr < 4; ++rr) {
        const int j = wrow * 64 + mi * 16 + q * 4 + rr;
#pragma unroll
        for (int ni = 0; ni < 4; ++ni) {
          const int cc = wcol * 64 + ni * 16 + l15;
          const int c = blockcol + cc;
          float x = acc[mi][ni][rr] + pv[ni] + Qm[((size_t)b * 128 + j) * 512 + c];
          float e4 = (x >= 0.f) ? x : 0.2f * x;
          *(bfloat*)(smem + (size_t)j * 256 + (((cc >> 3) ^ (j & 15)) * 16) + (cc & 7) * 2) =
              __float2bfloat16(e4);
        }
      }
    __syncthreads();
    // per wave: rows jb..jb+31, K=128 (4 steps), N=16 (h valid 0..7)
    f32x4 acc2[2];
    acc2[0] = (f32x4){0.f, 0.f, 0.f, 0.f};
    acc2[1] = (f32x4){0.f, 0.f, 0.f, 0.f};
    const int jb = wave * 32;
#pragma unroll
    for (int ks = 0; ks < 4; ++ks) {
      const int gA = ((ks * 4 + q) ^ l15) * 16;
      bf16x8 a0 = *(const bf16x8*)(smem + (size_t)(jb + l15) * 256 + gA);
      bf16x8 a1 = *(const bf16x8*)(smem + (size_t)(jb + 16 + l15) * 256 + gA);
      bf16x8 bb = *(const bf16x8*)(smem + 49152 + (size_t)l15 * 256 + gA);
      acc2[0] = __builtin_amdgcn_mfma_f32_16x16x32_bf16(a0, bb, acc2[0], 0, 0, 0);
      acc2[1] = __builtin_amdgcn_mfma_f32_16x16x32_bf16(a1, bb, acc2[1], 0, 0, 0);
    }
#pragma unroll
    for (int mi2 = 0; mi2 < 2; ++mi2)
#pragma unroll
      for (int rr = 0; rr < 4; ++rr) {
        if (l15 < 8) {
          const int j = jb + mi2 * 16 + q * 4 + rr;
          logits4[(((size_t)bn * 512 + bm) * 128 + j) * 8 + l15] = acc2[mi2][rr];
        }
      }
  }
}

// K6: out = E + u@Wu2 + b. One block owns one 64-row chunk; BK=32 (36KB LDS).
// Grid swizzled so chunk c runs on XCD (c>>1)&7 (where k3 wrote u & Ebf16).
__global__ __launch_bounds__(512) void k6_edge_out(const bfloat* WtC, const void* Wu2b,
                                                   const void* E, const int* flag, void* dout) {
  const int f = *flag;
  __shared__ __align__(16) char smem[36864];
  char* sA = smem;          // 64 rows x 64B
  char* sB = smem + 4096;   // 512 rows x 64B
  f32x4 acc[2][8];
#pragma unroll
  for (int mi = 0; mi < 2; ++mi)
#pragma unroll
    for (int ni = 0; ni < 8; ++ni) acc[mi][ni] = (f32x4){0.f, 0.f, 0.f, 0.f};

  const int e = blockIdx.x & 7;
  const int x = blockIdx.x >> 3;
  const int bm = 2 * e + 16 * (x >> 1) + (x & 1);  // chunk 0..1023, XCD = (bm>>1)&7 == e
  const int t = threadIdx.x;
  const int lane = t & 63;
  const int wave = t >> 6;
  const int wm = wave >> 2, wn = wave & 3;
  const int l15 = lane & 15;
  const int q = lane >> 4;
  const size_t r0 = (size_t)bm * 64;
  const char* ua = (const char*)dout +
                   (f ? (1048576 + (size_t)bm * 131072 + 65536) : (524288 + (size_t)bm * 65536));

  for (int kt = 0; kt < 16; ++kt) {
    __syncthreads();
    const int k0 = kt * 32;
    if (t < 256) {
      const int row = t >> 2;
      const int gseg = (t & 3) ^ ((row >> 1) & 3);
      g2l16(ua + (size_t)row * 1024 + (size_t)(k0 + gseg * 8) * 2, sA + wave * 64 * 16);
    }
#pragma unroll
    for (int c = 0; c < 4; ++c) {
      const int idx = c * 512 + t;
      const int row = idx >> 2;
      const int gseg = (idx & 3) ^ ((row >> 1) & 3);
      g2l16(WtC + (size_t)row * 512 + k0 + gseg * 8, sB + (c * 512 + wave * 64) * 16);
    }
    __syncthreads();
    bf16x8 afr[2], bfr[8];
#pragma unroll
    for (int mi = 0; mi < 2; ++mi) {
      const int r = wm * 32 + mi * 16 + l15;
      afr[mi] = *(const bf16x8*)(sA + ((size_t)r * 32 + (q ^ ((r >> 1) & 3)) * 8) * 2);
    }
#pragma unroll
    for (int ni = 0; ni < 8; ++ni) {
      const int r = wn * 128 + ni * 16 + l15;
      bfr[ni] = *(const bf16x8*)(sB + ((size_t)r * 32 + (q ^ ((r >> 1) & 3)) * 8) * 2);
    }
#pragma unroll
    for (int mi = 0; mi < 2; ++mi)
#pragma unroll
      for (int ni = 0; ni < 8; ++ni)
        acc[mi][ni] = __builtin_amdgcn_mfma_f32_16x16x32_bf16(afr[mi], bfr[ni], acc[mi][ni], 0, 0, 0);
  }
  // hoisted bias
  float wb[8];
#pragma unroll
  for (int ni = 0; ni < 8; ++ni) wb[ni] = ldf(Wu2b, wn * 128 + ni * 16 + l15, f);
  // residual reads (before barrier; this block's own byte range)
  const bfloat* eres = (const bfloat*)((const char*)dout + 1048576 + (size_t)bm * 131072);
#pragma unroll
  for (int mi = 0; mi < 2; ++mi)
#pragma unroll
    for (int rr = 0; rr < 4; ++rr) {
      const int j = wm * 32 + mi * 16 + q * 4 + rr;
#pragma unroll
      for (int ni = 0; ni < 8; ++ni) {
        const int c = wn * 128 + ni * 16 + l15;
        float r = f ? __bfloat162float(eres[(size_t)j * 512 + c])
                    : __bfloat162float(((const bfloat*)E)[(r0 + j) * 512 + c]);
        acc[mi][ni][rr] += wb[ni] + r;
      }
    }
  __syncthreads();  // all residual reads drained before overwriting the range
#pragma unroll
  for (int mi = 0; mi < 2; ++mi)
#pragma unroll
    for (int rr = 0; rr < 4; ++rr) {
      const int j = wm * 32 + mi * 16 + q * 4 + rr;
      const size_t row = r0 + j;
#pragma unroll
      for (int ni = 0; ni < 8; ++ni) {
        const int c = wn * 128 + ni * 16 + l15;
        stf(dout, 262144 + row * 512 + c, acc[mi][ni][rr], f);
      }
    }
}

__global__ __launch_bounds__(128) void softmax_mean(const float* logits4, const void* adj,
                                                    const int* flag, float* amean) {
  const int f = *flag;
  const int bi = blockIdx.x;
  const int j = threadIdx.x;
  __shared__ float red[128];
  float macc = 0.f;
  for (int hh = 0; hh < 8; ++hh) {
    float x = 0.f;
#pragma unroll
    for (int s = 0; s < 4; ++s)
      x += logits4[(((size_t)s * 512 + bi) * 128 + j) * 8 + hh];
    red[j] = x;
    __syncthreads();
    for (int s = 64; s > 0; s >>= 1) {
      if (j < s) red[j] = fmaxf(red[j], red[j + s]);
      __syncthreads();
    }
    float mx = red[0];
    __syncthreads();
    float ex = __expf(x - mx);
    red[j] = ex;
    __syncthreads();
    for (int s = 64; s > 0; s >>= 1) {
      if (j < s) red[j] += red[j + s];
      __syncthreads();
    }
    float sum = red[0];
    __syncthreads();
    macc += ex / sum;
  }
  amean[(size_t)bi * 128 + j] = macc * 0.125f * ldf(adj, (size_t)bi * 128 + j, f);
}

// fused aggregate + Wo + LayerNorm
__global__ __launch_bounds__(256) void node_fused(const float* amean, const float* msg,
                                                  const void* Wo, const void* Wob,
                                                  const void* node, const void* lng,
                                                  const void* lnb, const int* flag, void* dout) {
  const int f = *flag;
  const int bi = blockIdx.x;
  const int b = bi >> 7;
  const int t = threadIdx.x;
  __shared__ float am[128];
  __shared__ float sAgg[512];
  __shared__ float red[256];
  if (t < 128) am[t] = amean[(size_t)bi * 128 + t];
  __syncthreads();
  float a0 = 0.f, a1 = 0.f;
#pragma unroll 4
  for (int jj = 0; jj < 128; ++jj) {
    const float* mr = msg + ((size_t)b * 128 + jj) * 512;
    a0 += am[jj] * mr[t];
    a1 += am[jj] * mr[t + 256];
  }
  sAgg[t] = a0;
  sAgg[t + 256] = a1;
  __syncthreads();
  float v0 = 0.f, v1 = 0.f;
#pragma unroll 4
  for (int k = 0; k < 512; ++k) {
    float a = sAgg[k];
    v0 += a * ldf(Wo, (size_t)k * 512 + t, f);
    v1 += a * ldf(Wo, (size_t)k * 512 + t + 256, f);
  }
  v0 += ldf(Wob, t, f) + ldf(node, (size_t)bi * 512 + t, f);
  v1 += ldf(Wob, t + 256, f) + ldf(node, (size_t)bi * 512 + t + 256, f);
  red[t] = v0 + v1;
  __syncthreads();
  for (int s = 128; s > 0; s >>= 1) {
    if (t < s) red[t] += red[t + s];
    __syncthreads();
  }
  float mean = red[0] * (1.f / 512.f);
  __syncthreads();
  red[t] = (v0 - mean) * (v0 - mean) + (v1 - mean) * (v1 - mean);
  __syncthreads();
  for (int s = 128; s > 0; s >>= 1) {
    if (t < s) red[t] += red[t + s];
    __syncthreads();
  }
  float var = red[0] * (1.f / 512.f);
  float inv = rsqrtf(var + 1e-5f);
  stf(dout, (size_t)bi * 512 + t, (v0 - mean) * inv * ldf(lng, t, f) + ldf(lnb, t, f), f);
  stf(dout, (size_t)bi * 512 + t + 256,
      (v1 - mean) * inv * ldf(lng, t + 256, f) + ldf(lnb, t + 256, f), f);
}

extern "C" void kernel_launch(void* const* d_in, const int* in_sizes, int n_in, void* d_out,
                              int out_size, void* d_ws, size_t ws_size, hipStream_t stream) {
  (void)in_sizes; (void)n_in; (void)out_size; (void)ws_size;
  const void* node = d_in[0];
  const void* edge = d_in[1];
  const void* adj = d_in[2];
  const void* Wn_w = d_in[3];
  const void* Wn_b = d_in[4];
  const void* We1_w = d_in[5];
  const void* We1_b = d_in[6];
  const void* We2_w = d_in[7];
  // d_in[8] = We2_b: constant over j -> cancels in softmax, unused.
  const void* Wm_w = d_in[9];
  const void* Wm_b = d_in[10];
  const void* Wu1_w = d_in[11];
  const void* Wu1_b = d_in[12];
  const void* Wu2_w = d_in[13];
  const void* Wu2_b = d_in[14];
  const void* Wo_w = d_in[15];
  const void* Wo_b = d_in[16];
  const void* ln_g = d_in[17];
  const void* ln_b = d_in[18];

  char* w = (char*)d_ws;
  int* flag = (int*)w;        w += 256;
  float* h = (float*)w;       w += 262144 * 4;
  float* P1 = (float*)w;      w += 262144 * 4;
  float* Q1 = (float*)w;      w += 262144 * 4;
  float* P2 = (float*)w;      w += 262144 * 4;
  float* Q2 = (float*)w;      w += 262144 * 4;
  float* msg = (float*)w;     w += 262144 * 4;
  float* logits4 = (float*)w; w += (size_t)4 * 524288 * 4;  // [4][512][128][8] fp32 = 8MB
  float* amean = (float*)w;   w += 65536 * 4;
  bfloat* WtA = (bfloat*)w;   w += 262144 * 2;
  bfloat* WtB = (bfloat*)w;   w += 262144 * 2;
  bfloat* WtC = (bfloat*)w;   w += 262144 * 2;
  // total ~15.3MB

  detect_dtype<<<1, 256, 0, stream>>>((const unsigned short*)node, flag);
  cvt_edge<<<16384, 256, 0, stream>>>((const float*)edge, flag, d_out);
  transpose3<<<3072, 256, 0, stream>>>(We1_w, Wu1_w, Wu2_w, flag, WtA, WtB, WtC);
  small_gemm<<<128, 256, 0, stream>>>(node, 0, Wn_w, 0, Wn_b, flag, h);
  fused5<<<dim3(128, 5), 256, 0, stream>>>(h, We1_w, We1_b, Wu1_w, Wu1_b, Wm_w, Wm_b, flag,
                                           P1, Q1, P2, Q2, msg);
  k3_edge_mlp<<<4096, 256, 0, stream>>>(edge, WtA, WtB, P1, Q1, P2, Q2, We2_w, flag,
                                        logits4, d_out);
  softmax_mean<<<512, 128, 0, stream>>>(logits4, adj, flag, amean);
  node_fused<<<512, 256, 0, stream>>>(amean, msg, Wo_w, Wo_b, node, ln_g, ln_b, flag, d_out);
  k6_edge_out<<<1024, 512, 0, stream>>>(WtC, Wu2_b, edge, flag, d_out);
}

// Round 2
// 732.822 us; speedup vs baseline: 1.1939x; 1.0272x over previous
//
#include <hip/hip_runtime.h>
#include <hip/hip_bf16.h>

// GraphConvLayer B=4,N=128,D=512,H=8. Input dtype (bf16|fp32) runtime-detected
// -> flag in ws; output dtype follows input dtype.
// f==1: E pre-converted to bf16 into d_out's outE region, chunk-layout:
//   chunk c (64 rows) occupies bytes [1048576 + c*131072, +131072):
//   [Ebf16 64x1024B | u 64x1024B]. outE fp32 rows of chunk c = same byte range;
//   k6 block owns one chunk: reads Ebf16+u, barrier, overwrites with fp32 out.
// f==0: E read from d_in (bf16); u chunks at dout+524288+c*65536.
// XCD-locality chain: cvt_edge, k3, k6 grids swizzled so chunk c is written and
// read on XCD (c>>1)&7 (k3 block bm -> XCD bm&7; its chunks are 2bm,2bm+1).
// k3: BK=32, 16 K-iters, 3-deep counted-vmcnt pipeline (T3+T4): stage(t+2) after
//   raw s_barrier, s_waitcnt vmcnt(4) at iter top. LDS 52KB -> epilogues reuse.
//   Swizzle f(row)=(row>>1)&3 (r2 fix: row&3 gave 4-way bank conflicts at 64B
//   row stride; (row>>1)&3 spreads frag reads over 8 bank-groups, 2-way=free).
//   Attn epilogue: bf16 e-image in LDS + MFMA vs zero-padded We2 tile.
// k6 (r2): same 3-deep counted-vmcnt pipeline. LDS 108KB (3x4K A | 3x32K B),
//   5 load-instr/tile (1 A + 4 B), wave-uniform (waves 4-7 duplicate A loads to
//   identical LDS bytes). vmcnt(5) at iter top, stage(kt+2) after barrier.
// softmax_mean (r2): shfl_xor-based 8h-wide reductions, 3 barriers (was 112).

typedef __bf16  bf16x8 __attribute__((ext_vector_type(8)));
typedef float   f32x4  __attribute__((ext_vector_type(4)));
typedef __hip_bfloat16 bfloat;

#define AS1 __attribute__((address_space(1)))
#define AS3 __attribute__((address_space(3)))

__device__ __forceinline__ void g2l16(const void* g, void* l) {
  __builtin_amdgcn_global_load_lds((AS1 void*)g, (AS3 void*)l, 16, 0, 0);
}

__device__ __forceinline__ float ldf(const void* p, size_t i, int f) {
  return f ? ((const float*)p)[i] : __bfloat162float(((const bfloat*)p)[i]);
}
__device__ __forceinline__ void stf(void* p, size_t i, float v, int f) {
  if (f) ((float*)p)[i] = v;
  else   ((bfloat*)p)[i] = __float2bfloat16(v);
}

// tanh-form GELU (max abs err ~3e-4 vs exact erf form; well under threshold)
__device__ __forceinline__ float gelu_f(float x) {
  float y = 0.7978845608028654f * (x + 0.044715f * x * x * x);
  float e = __expf(2.0f * y);
  float t = 1.0f - 2.0f / (e + 1.0f);
  return 0.5f * x * (1.0f + t);
}

__global__ __launch_bounds__(256) void detect_dtype(const unsigned short* nu, int* flag) {
  __shared__ int bad;
  if (threadIdx.x == 0) bad = 0;
  __syncthreads();
  int local = 0;
  for (int i = threadIdx.x; i < 4096; i += 256) {
    int ex = (nu[i] >> 7) & 0xFF;
    if (ex >= 0xC0) local = 1;
  }
  if (local) atomicOr(&bad, 1);
  __syncthreads();
  if (threadIdx.x == 0) *flag = bad;
}

// f==1 only: E fp32 -> bf16 chunk layout in dout. Grid 16384, XCD-aligned:
// chunk c handled by blocks with blockIdx%8 == (c>>1)&7.
__global__ __launch_bounds__(256) void cvt_edge(const float* E, const int* flag, void* dout) {
  if (*flag == 0) return;
  const int e = blockIdx.x & 7;
  const int x = blockIdx.x >> 3;          // 0..2047
  const int m = x >> 5;                   // 0..63
  const int h = (x >> 4) & 1;
  const int s = x & 15;                   // 16 blocks per chunk
  const int c = 2 * e + 16 * m + h;       // chunk 0..1023
  const int t = threadIdx.x;
  const int rloc = s * 4 + (t >> 6);      // row within chunk 0..63
  const int c8 = t & 63;
  const float* src = E + ((size_t)c * 64 + rloc) * 512 + (size_t)c8 * 8;
  f32x4 lo = *(const f32x4*)src;
  f32x4 hi = *(const f32x4*)(src + 4);
  bf16x8 v;
  v[0] = (__bf16)lo[0]; v[1] = (__bf16)lo[1]; v[2] = (__bf16)lo[2]; v[3] = (__bf16)lo[3];
  v[4] = (__bf16)hi[0]; v[5] = (__bf16)hi[1]; v[6] = (__bf16)hi[2]; v[7] = (__bf16)hi[3];
  char* eb = (char*)dout + 1048576;
  *(bf16x8*)(eb + (size_t)c * 131072 + (size_t)rloc * 1024 + (size_t)c8 * 16) = v;
}

__global__ __launch_bounds__(256) void transpose3(const void* We1, const void* Wu1,
                                                  const void* Wu2, const int* flag,
                                                  bfloat* WtA, bfloat* WtB, bfloat* WtC) {
  const int f = *flag;
  int idx = blockIdx.x * 256 + threadIdx.x;
  int m = idx >> 18;
  int r = idx & 262143;
  int n = r >> 9, k = r & 511;
  size_t si = (size_t)k * 512 + n;
  float v;
  bfloat* dst;
  if (m == 0)      { v = ldf(We1, 524288 + si, f); dst = WtA; }
  else if (m == 1) { v = ldf(Wu1, 524288 + si, f); dst = WtB; }
  else             { v = ldf(Wu2, si, f);          dst = WtC; }
  dst[(size_t)n * 512 + k] = __float2bfloat16(v);
}

__global__ __launch_bounds__(256) void small_gemm(const void* A, int amode, const void* W,
                                                  size_t woff, const void* bias,
                                                  const int* flag, float* out) {
  const int f = *flag;
  const int af = amode ? 1 : f;
  __shared__ float sA[4][512];
  const int t = threadIdx.x;
  const int r0 = blockIdx.x * 4;
  for (int idx = t; idx < 2048; idx += 256)
    sA[idx >> 9][idx & 511] = ldf(A, (size_t)(r0 + (idx >> 9)) * 512 + (idx & 511), af);
  __syncthreads();
  float acc0[4] = {0.f, 0.f, 0.f, 0.f}, acc1[4] = {0.f, 0.f, 0.f, 0.f};
#pragma unroll 4
  for (int k = 0; k < 512; ++k) {
    float w0 = ldf(W, woff + (size_t)k * 512 + t, f);
    float w1 = ldf(W, woff + (size_t)k * 512 + t + 256, f);
#pragma unroll
    for (int r = 0; r < 4; ++r) {
      acc0[r] += sA[r][k] * w0;
      acc1[r] += sA[r][k] * w1;
    }
  }
  float b0 = bias ? ldf(bias, t, f) : 0.f;
  float b1 = bias ? ldf(bias, t + 256, f) : 0.f;
#pragma unroll
  for (int r = 0; r < 4; ++r) {
    out[(size_t)(r0 + r) * 512 + t] = acc0[r] + b0;
    out[(size_t)(r0 + r) * 512 + t + 256] = acc1[r] + b1;
  }
}

// 5 h-dependent 512^3 GEMMs in one launch
__global__ __launch_bounds__(256) void fused5(const float* h, const void* We1, const void* We1b,
                                              const void* Wu1, const void* Wu1b, const void* Wm,
                                              const void* Wmb, const int* flag, float* P1,
                                              float* Q1, float* P2, float* Q2, float* msgv) {
  const int f = *flag;
  const void* W;
  size_t woff = 0;
  const void* bias = nullptr;
  float* out;
  switch (blockIdx.y) {
    case 0:  W = We1; bias = We1b; out = P1; break;
    case 1:  W = We1; woff = 262144; out = Q1; break;
    case 2:  W = Wu1; bias = Wu1b; out = P2; break;
    case 3:  W = Wu1; woff = 262144; out = Q2; break;
    default: W = Wm;  bias = Wmb;  out = msgv; break;
  }
  __shared__ float sA[4][512];
  const int t = threadIdx.x;
  const int r0 = blockIdx.x * 4;
  for (int idx = t; idx < 2048; idx += 256)
    sA[idx >> 9][idx & 511] = h[(size_t)(r0 + (idx >> 9)) * 512 + (idx & 511)];
  __syncthreads();
  float acc0[4] = {0.f, 0.f, 0.f, 0.f}, acc1[4] = {0.f, 0.f, 0.f, 0.f};
#pragma unroll 4
  for (int k = 0; k < 512; ++k) {
    float w0 = ldf(W, woff + (size_t)k * 512 + t, f);
    float w1 = ldf(W, woff + (size_t)k * 512 + t + 256, f);
#pragma unroll
    for (int r = 0; r < 4; ++r) {
      acc0[r] += sA[r][k] * w0;
      acc1[r] += sA[r][k] * w1;
    }
  }
  float b0 = bias ? ldf(bias, t, f) : 0.f;
  float b1 = bias ? ldf(bias, t + 256, f) : 0.f;
#pragma unroll
  for (int r = 0; r < 4; ++r) {
    out[(size_t)(r0 + r) * 512 + t] = acc0[r] + b0;
    out[(size_t)(r0 + r) * 512 + t + 256] = acc1[r] + b1;
  }
}

// K3: 128x128 tile, BK=32, 16 K-iters, 3-deep counted-vmcnt LDS pipeline.
// LDS 52KB: A bufs [0,8K,16K), B bufs [24K,32K,40K), We2 tile [48K,52K).
// Epilogues reuse [0,32K) as the 128x128 bf16 swizzled image.
__global__ __launch_bounds__(256) void k3_edge_mlp(const void* E, const bfloat* WtA,
                                                   const bfloat* WtB, const float* P1,
                                                   const float* Q1, const float* P2,
                                                   const float* Q2, const void* We2,
                                                   const int* flag, float* logits4, void* dout) {
  const int f = *flag;
  __shared__ __align__(16) char smem[53248];
  f32x4 acc[4][4];
#pragma unroll
  for (int mi = 0; mi < 4; ++mi)
#pragma unroll
    for (int ni = 0; ni < 4; ++ni) acc[mi][ni] = (f32x4){0.f, 0.f, 0.f, 0.f};

  const int idx0 = blockIdx.x;                 // 0..4095
  const int bm = (idx0 >> 6) * 8 + (idx0 & 7); // XCD = bm&7
  const int bn = (idx0 >> 3) & 7;              // <4 attn, >=4 u
  const bool attn = bn < 4;
  const bfloat* Bg = attn ? WtA + (size_t)bn * 65536 : WtB + (size_t)(bn - 4) * 65536;
  const bfloat* Eb = (const bfloat*)E;
  const char* eb = (const char*)dout + 1048576;

  const int t = threadIdx.x;
  const int lane = t & 63;
  const int wave = t >> 6;
  const int wrow = wave >> 1, wcol = wave & 1;
  const int l15 = lane & 15;
  const int q = lane >> 4;
  const int blockcol = (attn ? bn : (bn - 4)) * 128;

  // per-thread stage sources (byte pointers); +64B per kt (32 bf16).
  // chunk L = c*256+t -> row = L>>2, phys slot p = L&3 holds chunk g = p^((row>>1)&3).
  const int row0 = t >> 2, p0 = t & 3, g0 = p0 ^ ((row0 >> 1) & 3);
  const int row1 = 64 + row0, g1 = p0 ^ ((row1 >> 1) & 3);
  const char* srcB0 = (const char*)Bg + ((size_t)row0 * 512 + g0 * 8) * 2;
  const char* srcB1 = (const char*)Bg + ((size_t)row1 * 512 + g1 * 8) * 2;
  const char* srcA0;
  const char* srcA1;
  const int gr0 = bm * 128 + row0, gr1 = gr0 + 64;
  if (f) {
    srcA0 = eb + (size_t)(gr0 >> 6) * 131072 + (size_t)(gr0 & 63) * 1024 + (size_t)g0 * 16;
    srcA1 = eb + (size_t)(gr1 >> 6) * 131072 + (size_t)(gr1 & 63) * 1024 + (size_t)g1 * 16;
  } else {
    srcA0 = (const char*)Eb + ((size_t)gr0 * 512 + g0 * 8) * 2;
    srcA1 = (const char*)Eb + ((size_t)gr1 * 512 + g1 * 8) * 2;
  }
  const int dst0 = wave * 1024;           // + lane*16 added by HW
  const int dst1 = 4096 + wave * 1024;

  auto stage = [&](int kt2, int sel2) {
    char* dA = smem + sel2 * 8192;
    char* dB = smem + 24576 + sel2 * 8192;
    const int koff = kt2 * 64;
    g2l16(srcA0 + koff, dA + dst0);
    g2l16(srcA1 + koff, dA + dst1);
    g2l16(srcB0 + koff, dB + dst0);
    g2l16(srcB1 + koff, dB + dst1);
  };

  stage(0, 0);
  stage(1, 1);

  if (attn) {
    // fill sWe2 [16][128] bf16 at 48K: row n (h, zero-pad n>=8), swizzled like image
    for (int idx = t; idx < 2048; idx += 256) {
      const int n = idx >> 7, k = idx & 127;
      float v = (n < 8) ? ldf(We2, (size_t)(blockcol + k) * 8 + n, f) : 0.f;
      *(bfloat*)(smem + 49152 + (size_t)n * 256 + (((k >> 3) ^ n) * 16) + (k & 7) * 2) =
          __float2bfloat16(v);
    }
  }

  // frag byte offsets within an 8KB buffer (row stride 64B, XOR'd chunk)
  // swizzle (row>>1)&3: frag reads spread over 8 bank-groups (2-way = free)
  const int fA = (wrow * 64 + l15) * 64 + ((q ^ ((l15 >> 1) & 3)) * 16);
  const int fB = (wcol * 64 + l15) * 64 + ((q ^ ((l15 >> 1) & 3)) * 16);

#pragma unroll
  for (int kt = 0; kt < 16; ++kt) {
    if (kt < 15) asm volatile("s_waitcnt vmcnt(4)" ::: "memory");
    else         asm volatile("s_waitcnt vmcnt(0)" ::: "memory");
    __builtin_amdgcn_s_barrier();
    if (kt < 14) stage(kt + 2, (kt + 2) % 3);
    const char* A = smem + (kt % 3) * 8192;
    const char* B = smem + 24576 + (kt % 3) * 8192;
    bf16x8 afr[4], bfr[4];
#pragma unroll
    for (int mi = 0; mi < 4; ++mi) afr[mi] = *(const bf16x8*)(A + fA + mi * 1024);
#pragma unroll
    for (int ni = 0; ni < 4; ++ni) bfr[ni] = *(const bf16x8*)(B + fB + ni * 1024);
#pragma unroll
    for (int mi = 0; mi < 4; ++mi)
#pragma unroll
      for (int ni = 0; ni < 4; ++ni)
        acc[mi][ni] =
            __builtin_amdgcn_mfma_f32_16x16x32_bf16(afr[mi], bfr[ni], acc[mi][ni], 0, 0, 0);
  }

  const int b = bm >> 7;
  const float* P = attn ? P1 : P2;
  const float* Qm = attn ? Q1 : Q2;
  // hoisted P (row-constant per block): global col = blockcol + wcol*64 + ni*16 + l15
  float pv[4];
#pragma unroll
  for (int ni = 0; ni < 4; ++ni)
    pv[ni] = P[(size_t)bm * 512 + blockcol + wcol * 64 + ni * 16 + l15];

  __syncthreads();  // last tile's frag reads retired before smem reuse as image

  if (!attn) {
    // write phase: val(j, cc) at j*256 + ((cc>>3)^(j&15))*16 + (cc&7)*2
#pragma unroll
    for (int mi = 0; mi < 4; ++mi)
#pragma unroll
      for (int rr = 0; rr < 4; ++rr) {
        const int j = wrow * 64 + mi * 16 + q * 4 + rr;
#pragma unroll
        for (int ni = 0; ni < 4; ++ni) {
          const int cc = wcol * 64 + ni * 16 + l15;
          const int c = blockcol + cc;
          float x = acc[mi][ni][rr] + pv[ni] + Qm[((size_t)b * 128 + j) * 512 + c];
          *(bfloat*)(smem + (size_t)j * 256 + (((cc >> 3) ^ (j & 15)) * 16) + (cc & 7) * 2) =
              __float2bfloat16(gelu_f(x));
        }
      }
    __syncthreads();
    // read phase: 16B/lane, lanes 0..15 cover one full 256B local row -> coalesced
    char* ubase = (char*)dout + (f ? (1048576 + 65536) : 524288);
    const size_t blkstride = f ? 131072 : 65536;
#pragma unroll
    for (int rd = 0; rd < 8; ++rd) {
      const int j = rd * 16 + (t >> 4);
      const int ch = t & 15;
      f32x4 v = *(const f32x4*)(smem + (size_t)j * 256 + ((ch ^ (j & 15)) * 16));
      const size_t m = (size_t)bm * 128 + j;
      *(f32x4*)(ubase + (m >> 6) * blkstride + (m & 63) * 1024 + (size_t)blockcol * 2 +
                (size_t)ch * 16) = v;
    }
  } else {
    // write lrelu(e) bf16 into the image, then logits-partial = image @ sWe2 via MFMA
#pragma unroll
    for (int mi = 0; mi < 4; ++mi)
#pragma unroll
      for (int rr = 0; rr < 4; ++rr) {
        const int j = wrow * 64 + mi * 16 + q * 4 + rr;
#pragma unroll
        for (int ni = 0; ni < 4; ++ni) {
          const int cc = wcol * 64 + ni * 16 + l15;
          const int c = blockcol + cc;
          float x = acc[mi][ni][rr] + pv[ni] + Qm[((size_t)b * 128 + j) * 512 + c];
          float e4 = (x >= 0.f) ? x : 0.2f * x;
          *(bfloat*)(smem + (size_t)j * 256 + (((cc >> 3) ^ (j & 15)) * 16) + (cc & 7) * 2) =
              __float2bfloat16(e4);
        }
      }
    __syncthreads();
    // per wave: rows jb..jb+31, K=128 (4 steps), N=16 (h valid 0..7)
    f32x4 acc2[2];
    acc2[0] = (f32x4){0.f, 0.f, 0.f, 0.f};
    acc2[1] = (f32x4){0.f, 0.f, 0.f, 0.f};
    const int jb = wave * 32;
#pragma unroll
    for (int ks = 0; ks < 4; ++ks) {
      const int gA = ((ks * 4 + q) ^ l15) * 16;
      bf16x8 a0 = *(const bf16x8*)(smem + (size_t)(jb + l15) * 256 + gA);
      bf16x8 a1 = *(const bf16x8*)(smem + (size_t)(jb + 16 + l15) * 256 + gA);
      bf16x8 bb = *(const bf16x8*)(smem + 49152 + (size_t)l15 * 256 + gA);
      acc2[0] = __builtin_amdgcn_mfma_f32_16x16x32_bf16(a0, bb, acc2[0], 0, 0, 0);
      acc2[1] = __builtin_amdgcn_mfma_f32_16x16x32_bf16(a1, bb, acc2[1], 0, 0, 0);
    }
#pragma unroll
    for (int mi2 = 0; mi2 < 2; ++mi2)
#pragma unroll
      for (int rr = 0; rr < 4; ++rr) {
        if (l15 < 8) {
          const int j = jb + mi2 * 16 + q * 4 + rr;
          logits4[(((size_t)bn * 512 + bm) * 128 + j) * 8 + l15] = acc2[mi2][rr];
        }
      }
  }
}

// K6: out = E + u@Wu2 + b. One block owns one 64-row chunk; BK=32, 16 K-iters.
// r2: 3-deep counted-vmcnt pipeline. LDS 108KB: A bufs 3x4KB [0,12K),
// B bufs 3x32KB [12K,108K+12K). 5 load-instr per tile (1 A + 4 B); waves 4-7
// duplicate the A load (identical src+dst bytes) so vmcnt is wave-uniform.
// Grid swizzled so chunk c runs on XCD (c>>1)&7 (where k3 wrote u & Ebf16).
__global__ __launch_bounds__(512) void k6_edge_out(const bfloat* WtC, const void* Wu2b,
                                                   const void* E, const int* flag, void* dout) {
  const int f = *flag;
  __shared__ __align__(16) char smem[110592];
  f32x4 acc[2][8];
#pragma unroll
  for (int mi = 0; mi < 2; ++mi)
#pragma unroll
    for (int ni = 0; ni < 8; ++ni) acc[mi][ni] = (f32x4){0.f, 0.f, 0.f, 0.f};

  const int e = blockIdx.x & 7;
  const int x = blockIdx.x >> 3;
  const int bm = 2 * e + 16 * (x >> 1) + (x & 1);  // chunk 0..1023, XCD = (bm>>1)&7 == e
  const int t = threadIdx.x;
  const int lane = t & 63;
  const int wave = t >> 6;
  const int wm = wave >> 2, wn = wave & 3;
  const int l15 = lane & 15;
  const int q = lane >> 4;
  const size_t r0 = (size_t)bm * 64;
  const char* ua = (const char*)dout +
                   (f ? (1048576 + (size_t)bm * 131072 + 65536) : (524288 + (size_t)bm * 65536));

  // per-thread stage sources (byte ptrs), +64B per kt (32 bf16).
  // A: iA = t&255 -> row = iA>>2 (0..63), p = iA&3 holds chunk g = p^((row>>1)&3).
  const int iA = t & 255;
  const int rowA = iA >> 2, pA = iA & 3, gA = pA ^ ((rowA >> 1) & 3);
  const char* srcA = ua + (size_t)rowA * 1024 + (size_t)gA * 16;
  const int dstA = (wave & 3) * 1024;  // + lane*16 added by HW
  // B: idx = c*512+t -> row = idx>>2 (0..511), p = idx&3, g = p^((row>>1)&3)
  const char* srcB[4];
  int dstB[4];
#pragma unroll
  for (int c = 0; c < 4; ++c) {
    const int idx = c * 512 + t;
    const int row = idx >> 2, p = idx & 3, g = p ^ ((row >> 1) & 3);
    srcB[c] = (const char*)WtC + ((size_t)row * 512 + g * 8) * 2;
    dstB[c] = (c * 512 + wave * 64) * 16;
  }

  auto stage = [&](int kt2, int sel2) {
    const int koff = kt2 * 64;
    char* dA = smem + sel2 * 4096;
    char* dB = smem + 12288 + sel2 * 32768;
    g2l16(srcA + koff, dA + dstA);
#pragma unroll
    for (int c = 0; c < 4; ++c) g2l16(srcB[c] + koff, dB + dstB[c]);
  };

  stage(0, 0);
  stage(1, 1);

  // frag byte offsets within buffers (row stride 64B, swizzle (row>>1)&3)
  const int swz = (q ^ ((l15 >> 1) & 3)) * 16;
  const int fAo = (wm * 32 + l15) * 64 + swz;
  const int fBo = (wn * 128 + l15) * 64 + swz;

#pragma unroll
  for (int kt = 0; kt < 16; ++kt) {
    if (kt < 15) asm volatile("s_waitcnt vmcnt(5)" ::: "memory");
    else         asm volatile("s_waitcnt vmcnt(0)" ::: "memory");
    __builtin_amdgcn_s_barrier();
    if (kt < 14) stage(kt + 2, (kt + 2) % 3);
    const char* sA = smem + (kt % 3) * 4096;
    const char* sB = smem + 12288 + (kt % 3) * 32768;
    bf16x8 afr[2], bfr[8];
#pragma unroll
    for (int mi = 0; mi < 2; ++mi) afr[mi] = *(const bf16x8*)(sA + fAo + mi * 1024);
#pragma unroll
    for (int ni = 0; ni < 8; ++ni) bfr[ni] = *(const bf16x8*)(sB + fBo + ni * 1024);
#pragma unroll
    for (int mi = 0; mi < 2; ++mi)
#pragma unroll
      for (int ni = 0; ni < 8; ++ni)
        acc[mi][ni] = __builtin_amdgcn_mfma_f32_16x16x32_bf16(afr[mi], bfr[ni], acc[mi][ni], 0, 0, 0);
  }
  // hoisted bias
  float wb[8];
#pragma unroll
  for (int ni = 0; ni < 8; ++ni) wb[ni] = ldf(Wu2b, wn * 128 + ni * 16 + l15, f);
  // residual reads (before barrier; this block's own byte range)
  const bfloat* eres = (const bfloat*)((const char*)dout + 1048576 + (size_t)bm * 131072);
#pragma unroll
  for (int mi = 0; mi < 2; ++mi)
#pragma unroll
    for (int rr = 0; rr < 4; ++rr) {
      const int j = wm * 32 + mi * 16 + q * 4 + rr;
#pragma unroll
      for (int ni = 0; ni < 8; ++ni) {
        const int c = wn * 128 + ni * 16 + l15;
        float r = f ? __bfloat162float(eres[(size_t)j * 512 + c])
                    : __bfloat162float(((const bfloat*)E)[(r0 + j) * 512 + c]);
        acc[mi][ni][rr] += wb[ni] + r;
      }
    }
  __syncthreads();  // all residual reads drained before overwriting the range
#pragma unroll
  for (int mi = 0; mi < 2; ++mi)
#pragma unroll
    for (int rr = 0; rr < 4; ++rr) {
      const int j = wm * 32 + mi * 16 + q * 4 + rr;
      const size_t row = r0 + j;
#pragma unroll
      for (int ni = 0; ni < 8; ++ni) {
        const int c = wn * 128 + ni * 16 + l15;
        stf(dout, 262144 + row * 512 + c, acc[mi][ni][rr], f);
      }
    }
}

// r2: shfl_xor-based; 8 h's reduced simultaneously, 3 barriers total.
__global__ __launch_bounds__(128) void softmax_mean(const float* logits4, const void* adj,
                                                    const int* flag, float* amean) {
  const int f = *flag;
  const int bi = blockIdx.x;
  const int j = threadIdx.x;   // 0..127
  const int wv = j >> 6;
  __shared__ float sred[2][8];
  f32x4 v0 = (f32x4){0.f, 0.f, 0.f, 0.f}, v1 = (f32x4){0.f, 0.f, 0.f, 0.f};
#pragma unroll
  for (int s = 0; s < 4; ++s) {
    const float* p = logits4 + (((size_t)s * 512 + bi) * 128 + j) * 8;
    v0 += *(const f32x4*)p;
    v1 += *(const f32x4*)(p + 4);
  }
  float xv[8], m[8];
#pragma unroll
  for (int k = 0; k < 4; ++k) { xv[k] = v0[k]; xv[4 + k] = v1[k]; }
#pragma unroll
  for (int h = 0; h < 8; ++h) m[h] = xv[h];
#pragma unroll
  for (int o = 1; o < 64; o <<= 1)
#pragma unroll
    for (int h = 0; h < 8; ++h) m[h] = fmaxf(m[h], __shfl_xor(m[h], o));
  if ((j & 63) == 0) {
#pragma unroll
    for (int h = 0; h < 8; ++h) sred[wv][h] = m[h];
  }
  __syncthreads();
  float ex[8], s8[8];
#pragma unroll
  for (int h = 0; h < 8; ++h) {
    float mx = fmaxf(sred[0][h], sred[1][h]);
    ex[h] = __expf(xv[h] - mx);
    s8[h] = ex[h];
  }
#pragma unroll
  for (int o = 1; o < 64; o <<= 1)
#pragma unroll
    for (int h = 0; h < 8; ++h) s8[h] += __shfl_xor(s8[h], o);
  __syncthreads();  // sred reads above done before overwrite
  if ((j & 63) == 0) {
#pragma unroll
    for (int h = 0; h < 8; ++h) sred[wv][h] = s8[h];
  }
  __syncthreads();
  float macc = 0.f;
#pragma unroll
  for (int h = 0; h < 8; ++h) macc += ex[h] / (sred[0][h] + sred[1][h]);
  amean[(size_t)bi * 128 + j] = macc * 0.125f * ldf(adj, (size_t)bi * 128 + j, f);
}

// fused aggregate + Wo + LayerNorm
__global__ __launch_bounds__(256) void node_fused(const float* amean, const float* msg,
                                                  const void* Wo, const void* Wob,
                                                  const void* node, const void* lng,
                                                  const void* lnb, const int* flag, void* dout) {
  const int f = *flag;
  const int bi = blockIdx.x;
  const int b = bi >> 7;
  const int t = threadIdx.x;
  __shared__ float am[128];
  __shared__ float sAgg[512];
  __shared__ float red[256];
  if (t < 128) am[t] = amean[(size_t)bi * 128 + t];
  __syncthreads();
  float a0 = 0.f, a1 = 0.f;
#pragma unroll 4
  for (int jj = 0; jj < 128; ++jj) {
    const float* mr = msg + ((size_t)b * 128 + jj) * 512;
    a0 += am[jj] * mr[t];
    a1 += am[jj] * mr[t + 256];
  }
  sAgg[t] = a0;
  sAgg[t + 256] = a1;
  __syncthreads();
  float v0 = 0.f, v1 = 0.f;
#pragma unroll 4
  for (int k = 0; k < 512; ++k) {
    float a = sAgg[k];
    v0 += a * ldf(Wo, (size_t)k * 512 + t, f);
    v1 += a * ldf(Wo, (size_t)k * 512 + t + 256, f);
  }
  v0 += ldf(Wob, t, f) + ldf(node, (size_t)bi * 512 + t, f);
  v1 += ldf(Wob, t + 256, f) + ldf(node, (size_t)bi * 512 + t + 256, f);
  red[t] = v0 + v1;
  __syncthreads();
  for (int s = 128; s > 0; s >>= 1) {
    if (t < s) red[t] += red[t + s];
    __syncthreads();
  }
  float mean = red[0] * (1.f / 512.f);
  __syncthreads();
  red[t] = (v0 - mean) * (v0 - mean) + (v1 - mean) * (v1 - mean);
  __syncthreads();
  for (int s = 128; s > 0; s >>= 1) {
    if (t < s) red[t] += red[t + s];
    __syncthreads();
  }
  float var = red[0] * (1.f / 512.f);
  float inv = rsqrtf(var + 1e-5f);
  stf(dout, (size_t)bi * 512 + t, (v0 - mean) * inv * ldf(lng, t, f) + ldf(lnb, t, f), f);
  stf(dout, (size_t)bi * 512 + t + 256,
      (v1 - mean) * inv * ldf(lng, t + 256, f) + ldf(lnb, t + 256, f), f);
}

extern "C" void kernel_launch(void* const* d_in, const int* in_sizes, int n_in, void* d_out,
                              int out_size, void* d_ws, size_t ws_size, hipStream_t stream) {
  (void)in_sizes; (void)n_in; (void)out_size; (void)ws_size;
  const void* node = d_in[0];
  const void* edge = d_in[1];
  const void* adj = d_in[2];
  const void* Wn_w = d_in[3];
  const void* Wn_b = d_in[4];
  const void* We1_w = d_in[5];
  const void* We1_b = d_in[6];
  const void* We2_w = d_in[7];
  // d_in[8] = We2_b: constant over j -> cancels in softmax, unused.
  const void* Wm_w = d_in[9];
  const void* Wm_b = d_in[10];
  const void* Wu1_w = d_in[11];
  const void* Wu1_b = d_in[12];
  const void* Wu2_w = d_in[13];
  const void* Wu2_b = d_in[14];
  const void* Wo_w = d_in[15];
  const void* Wo_b = d_in[16];
  const void* ln_g = d_in[17];
  const void* ln_b = d_in[18];

  char* w = (char*)d_ws;
  int* flag = (int*)w;        w += 256;
  float* h = (float*)w;       w += 262144 * 4;
  float* P1 = (float*)w;      w += 262144 * 4;
  float* Q1 = (float*)w;      w += 262144 * 4;
  float* P2 = (float*)w;      w += 262144 * 4;
  float* Q2 = (float*)w;      w += 262144 * 4;
  float* msg = (float*)w;     w += 262144 * 4;
  float* logits4 = (float*)w; w += (size_t)4 * 524288 * 4;  // [4][512][128][8] fp32 = 8MB
  float* amean = (float*)w;   w += 65536 * 4;
  bfloat* WtA = (bfloat*)w;   w += 262144 * 2;
  bfloat* WtB = (bfloat*)w;   w += 262144 * 2;
  bfloat* WtC = (bfloat*)w;   w += 262144 * 2;
  // total ~15.3MB

  detect_dtype<<<1, 256, 0, stream>>>((const unsigned short*)node, flag);
  cvt_edge<<<16384, 256, 0, stream>>>((const float*)edge, flag, d_out);
  transpose3<<<3072, 256, 0, stream>>>(We1_w, Wu1_w, Wu2_w, flag, WtA, WtB, WtC);
  small_gemm<<<128, 256, 0, stream>>>(node, 0, Wn_w, 0, Wn_b, flag, h);
  fused5<<<dim3(128, 5), 256, 0, stream>>>(h, We1_w, We1_b, Wu1_w, Wu1_b, Wm_w, Wm_b, flag,
                                           P1, Q1, P2, Q2, msg);
  k3_edge_mlp<<<4096, 256, 0, stream>>>(edge, WtA, WtB, P1, Q1, P2, Q2, We2_w, flag,
                                        logits4, d_out);
  softmax_mean<<<512, 128, 0, stream>>>(logits4, adj, flag, amean);
  node_fused<<<512, 256, 0, stream>>>(amean, msg, Wo_w, Wo_b, node, ln_g, ln_b, flag, d_out);
  k6_edge_out<<<1024, 512, 0, stream>>>(WtC, Wu2_b, edge, flag, d_out);
}